// Round 1
// baseline (10775.066 us; speedup 1.0000x reference)
//
#include <hip/hip_runtime.h>
#include <cmath>

// Problem constants
constexpr int B_  = 16;    // batch
constexpr int N_  = 64;    // frames (scan length)
constexpr int K_  = 20;    // objects incl. image slot
constexpr int KM1 = 19;    // objects
constexpr int D_  = 4096;  // input feature dim
constexpr int DI_ = 1024;
constexpr int DO_ = 1024;
constexpr int H_  = 1024;
constexpr int G4_ = 4096;  // 4*H

static __device__ __forceinline__ float sigmoidf_(float x) {
  return 1.0f / (1.0f + expf(-x));
}

// 256-thread (4-wave) block sum reduction
static __device__ __forceinline__ float block_reduce_sum256(float v, float* red) {
  #pragma unroll
  for (int off = 32; off > 0; off >>= 1) v += __shfl_down(v, off);
  const int wid = threadIdx.x >> 6;
  if ((threadIdx.x & 63) == 0) red[wid] = v;
  __syncthreads();
  const float r = red[0] + red[1] + red[2] + red[3];
  __syncthreads();
  return r;
}

// obj_mask[r] = sum_d x[b, n, 1+kk, d],  r = (b*N + n)*19 + kk
__global__ __launch_bounds__(256) void mask_kernel(const float* __restrict__ x,
                                                   float* __restrict__ mask) {
  const int r = blockIdx.x;
  const int g = r / KM1, kk = r - g * KM1;
  const float4* xp = (const float4*)(x + ((size_t)g * K_ + 1 + kk) * D_);
  float v = 0.f;
  #pragma unroll
  for (int it = 0; it < 4; ++it) {
    const float4 t = xp[threadIdx.x + it * 256];
    v += (t.x + t.y) + (t.z + t.w);
  }
  __shared__ float red[4];
  const float s = block_reduce_sum256(v, red);
  if (threadIdx.x == 0) mask[r] = s;
}

// Generic fp32 GEMM: C[M,N] = (A @ B + bias) [* scale_row]
// AMODE 0: A row r at A + r*Kk (contiguous)
// AMODE 1: A row r is x[b,n,1+kk,:]  (r = (b*N+n)*19 + kk)
// AMODE 2: A row r is x[r/N... i.e. row r at A + r*K_*D_ (k=0 slice)
// BTRANS:  B element (k,n) at Bm[n*ldb + k] (row-major (N,K)); else Bm[k*ldb + n]
// Tiles: 128x128, BK=16, 256 threads, 8x8 per thread.
template<int AMODE, bool BTRANS, bool SCALE>
__global__ __launch_bounds__(256) void gemm_f32(
    const float* __restrict__ A, const float* __restrict__ Bm, const int ldb,
    const float* __restrict__ bias, const float* __restrict__ scale,
    float* __restrict__ C, const int Kk, const int Nn)
{
  constexpr int BM = 128, BN = 128, BK = 16;
  __shared__ float As[BK][BM + 4];
  __shared__ float Bs[BK][BN + 4];
  const int tid = threadIdx.x;
  const int m0 = blockIdx.x * BM, n0 = blockIdx.y * BN;
  const int tm = tid & 15, tn = tid >> 4;

  // Hoist A row pointers for the two staging sub-loads
  const float* arow[2];
  #pragma unroll
  for (int it = 0; it < 2; ++it) {
    const int m = (tid + it * 256) >> 2;
    const int row = m0 + m;
    if (AMODE == 0)      arow[it] = A + (size_t)row * Kk;
    else if (AMODE == 1) { const int g = row / KM1, kk2 = row - g * KM1;
                           arow[it] = A + ((size_t)g * K_ + 1 + kk2) * D_; }
    else                 arow[it] = A + (size_t)row * (K_ * D_);
  }
  const int akq = (tid & 3) * 4;

  float acc[8][8] = {};
  for (int k0 = 0; k0 < Kk; k0 += BK) {
    // stage A (128 x 16), transposed into As[k][m]
    #pragma unroll
    for (int it = 0; it < 2; ++it) {
      const int m = (tid + it * 256) >> 2;
      const float4 v = *(const float4*)(arow[it] + k0 + akq);
      As[akq + 0][m] = v.x; As[akq + 1][m] = v.y;
      As[akq + 2][m] = v.z; As[akq + 3][m] = v.w;
    }
    // stage B (16 x 128) into Bs[k][n]
    if (!BTRANS) {
      #pragma unroll
      for (int it = 0; it < 2; ++it) {
        const int idx = tid + it * 256;
        const int k = idx >> 5, n4 = (idx & 31) * 4;
        *(float4*)&Bs[k][n4] = *(const float4*)(Bm + (size_t)(k0 + k) * ldb + n0 + n4);
      }
    } else {
      #pragma unroll
      for (int it = 0; it < 2; ++it) {
        const int idx = tid + it * 256;
        const int kq = (idx & 3) * 4, nr = idx >> 2;
        const float4 v = *(const float4*)(Bm + (size_t)(n0 + nr) * ldb + k0 + kq);
        Bs[kq + 0][nr] = v.x; Bs[kq + 1][nr] = v.y;
        Bs[kq + 2][nr] = v.z; Bs[kq + 3][nr] = v.w;
      }
    }
    __syncthreads();
    #pragma unroll
    for (int k = 0; k < BK; ++k) {
      float av[8], bv[8];
      *(float4*)&av[0] = *(const float4*)&As[k][tm * 8];
      *(float4*)&av[4] = *(const float4*)&As[k][tm * 8 + 4];
      *(float4*)&bv[0] = *(const float4*)&Bs[k][tn * 8];
      *(float4*)&bv[4] = *(const float4*)&Bs[k][tn * 8 + 4];
      #pragma unroll
      for (int r = 0; r < 8; ++r)
        #pragma unroll
        for (int s = 0; s < 8; ++s)
          acc[r][s] = fmaf(av[r], bv[s], acc[r][s]);
    }
    __syncthreads();
  }
  #pragma unroll
  for (int r = 0; r < 8; ++r) {
    const int row = m0 + tm * 8 + r;
    const float sc = SCALE ? scale[row] : 1.0f;
    #pragma unroll
    for (int s4 = 0; s4 < 8; s4 += 4) {
      const int n = n0 + tn * 8 + s4;
      float4 o;
      o.x = (acc[r][s4 + 0] + bias[n + 0]) * sc;
      o.y = (acc[r][s4 + 1] + bias[n + 1]) * sc;
      o.z = (acc[r][s4 + 2] + bias[n + 2]) * sc;
      o.w = (acc[r][s4 + 3] + bias[n + 3]) * sc;
      *(float4*)(C + (size_t)row * Nn + n) = o;
    }
  }
}

// attn hidden partials: ahp[isl][b][j] = sum_{i in slice} hB[b][i] * Wah[i][j]
// grid (4 j-blocks, 8 i-slices), 256 threads
__global__ __launch_bounds__(256) void attn_h_kernel(
    const float* __restrict__ hB, const float* __restrict__ Wah, float* __restrict__ ahp)
{
  const int j = blockIdx.x * 256 + threadIdx.x;
  const int isl = blockIdx.y;
  float acc[B_] = {};
  for (int i0 = 0; i0 < 128; i0 += 4) {
    const int i = isl * 128 + i0;
    const float w0 = Wah[(size_t)(i + 0) * DO_ + j];
    const float w1 = Wah[(size_t)(i + 1) * DO_ + j];
    const float w2 = Wah[(size_t)(i + 2) * DO_ + j];
    const float w3 = Wah[(size_t)(i + 3) * DO_ + j];
    #pragma unroll
    for (int b = 0; b < B_; ++b) {
      const float4 hv = *(const float4*)(hB + b * H_ + i);  // wave-uniform scalar load
      acc[b] = fmaf(hv.x, w0, fmaf(hv.y, w1, fmaf(hv.z, w2, fmaf(hv.w, w3, acc[b]))));
    }
  }
  #pragma unroll
  for (int b = 0; b < B_; ++b) ahp[((size_t)isl * B_ + b) * DO_ + j] = acc[b];
}

// scores + softmax + w_obj, one block per batch element b
__global__ __launch_bounds__(256) void attn_rest_kernel(
    const float* __restrict__ ahp, const float* __restrict__ a,
    const float* __restrict__ wj, const float* __restrict__ mask,
    const int n, float* __restrict__ alphas_out, float* __restrict__ wobj)
{
  const int b = blockIdx.x, tid = threadIdx.x;
  __shared__ float ahs[DO_];
  __shared__ float red[4];
  __shared__ float sc[KM1];
  // reduce the 8 attn_h partials
  #pragma unroll
  for (int it = 0; it < 4; ++it) {
    const int j = tid + it * 256;
    float s = 0.f;
    #pragma unroll
    for (int sl = 0; sl < 8; ++sl) s += ahp[((size_t)sl * B_ + b) * DO_ + j];
    ahs[j] = s;
  }
  __syncthreads();
  const size_t rowbase = (size_t)(b * N_ + n) * KM1;
  for (int k = 0; k < KM1; ++k) {
    const float* ak = a + (rowbase + k) * DO_;
    float v = 0.f;
    #pragma unroll
    for (int it = 0; it < 4; ++it) {
      const int j = tid + it * 256;
      v = fmaf(tanhf(ahs[j] + ak[j]), wj[j], v);
    }
    const float s = block_reduce_sum256(v, red);
    if (tid == 0) sc[k] = s * mask[rowbase + k];
  }
  __syncthreads();
  // softmax over 19 (redundant per thread; sc broadcast from LDS)
  float mx = -1e30f;
  #pragma unroll
  for (int k = 0; k < KM1; ++k) mx = fmaxf(mx, sc[k]);
  float al[KM1];
  float ssum = 0.f;
  #pragma unroll
  for (int k = 0; k < KM1; ++k) { al[k] = expf(sc[k] - mx); ssum += al[k]; }
  const float inv = 1.0f / ssum;
  if (tid < KM1) alphas_out[b * KM1 + tid] = expf(sc[tid] - mx) * inv;
  // w_obj[b][j] = sum_k alpha_k * a[b,n,k,j]
  #pragma unroll
  for (int it = 0; it < 4; ++it) {
    const int j = tid + it * 256;
    float acc = 0.f;
    #pragma unroll
    for (int k = 0; k < KM1; ++k) acc = fmaf(al[k], a[(rowbase + k) * DO_ + j], acc);
    wobj[b * DO_ + j] = acc * inv;
  }
}

// LSTM gate partials for one layer, concatenated K = [x0 (1024), x1 (1024)]:
//   gp[ks][b][g] += sum_{k in slice} X[b][k] * W[g][co + k]
// grid (16 g-blocks of 256, 16 k-slices of 128), 128 threads (2 waves),
// thread tile 8g x 4b via transposed-W LDS.
__global__ __launch_bounds__(128) void gates_kernel(
    const float* __restrict__ x0, const float* __restrict__ x1,
    const float* __restrict__ W0, const int ld0, const int co0,
    const float* __restrict__ W1, const int ld1, const int co1,
    float* __restrict__ gp)
{
  constexpr int GT = 256, BK = 32, KSL = 128;
  __shared__ float Ws[BK][GT + 4];   // transposed: Ws[k][g]
  __shared__ float Xs[BK][20];       // transposed: Xs[k][b]
  const int tid = threadIdx.x;
  const int g0 = blockIdx.x * GT;
  const int ks = blockIdx.y;
  const int half = ks >> 3;
  const int koff = (ks & 7) * KSL;
  const float* X = half ? x1 : x0;
  const float* W = half ? W1 : W0;
  const int ld = half ? ld1 : ld0;
  const int co = half ? co1 : co0;
  const int tb = (tid & 3) * 4;        // b base (4 b per thread)
  const int tg = (tid >> 2) * 8;       // g base (8 g per thread)
  float acc[4][8] = {};                // [bi][gi]
  for (int k0 = 0; k0 < KSL; k0 += BK) {
    // stage W tile (256 g x 32 k), transposed
    #pragma unroll
    for (int it = 0; it < 16; ++it) {
      const int idx = tid + it * 128;
      const int kq = (idx & 7) * 4, gr = idx >> 3;
      const float4 v = *(const float4*)(W + (size_t)(g0 + gr) * ld + co + koff + k0 + kq);
      Ws[kq + 0][gr] = v.x; Ws[kq + 1][gr] = v.y;
      Ws[kq + 2][gr] = v.z; Ws[kq + 3][gr] = v.w;
    }
    // stage X tile (16 b x 32 k), transposed
    {
      const int xb = tid & 15, kq = (tid >> 4) * 4;
      const float4 v = *(const float4*)(X + (size_t)xb * H_ + koff + k0 + kq);
      Xs[kq + 0][xb] = v.x; Xs[kq + 1][xb] = v.y;
      Xs[kq + 2][xb] = v.z; Xs[kq + 3][xb] = v.w;
    }
    __syncthreads();
    #pragma unroll
    for (int k = 0; k < BK; ++k) {
      float wv[8], xv[4];
      *(float4*)&wv[0] = *(const float4*)&Ws[k][tg];
      *(float4*)&wv[4] = *(const float4*)&Ws[k][tg + 4];
      *(float4*)&xv[0] = *(const float4*)&Xs[k][tb];
      #pragma unroll
      for (int bi = 0; bi < 4; ++bi)
        #pragma unroll
        for (int gi = 0; gi < 8; ++gi)
          acc[bi][gi] = fmaf(wv[gi], xv[bi], acc[bi][gi]);
    }
    __syncthreads();
  }
  float* outp = gp + (size_t)ks * B_ * G4_;
  #pragma unroll
  for (int bi = 0; bi < 4; ++bi) {
    float* op = outp + (size_t)(tb + bi) * G4_ + g0 + tg;
    *(float4*)(op)     = *(const float4*)&acc[bi][0];
    *(float4*)(op + 4) = *(const float4*)&acc[bi][4];
  }
}

// layer-0 cell: gates = img_gates[(b,n)] (incl. b0) + sum of 16 partials
__global__ __launch_bounds__(256) void cell0_kernel(
    const float* __restrict__ gp, const float* __restrict__ img_gates, const int n,
    float* __restrict__ hA, float* __restrict__ cA)
{
  const int idx = blockIdx.x * 256 + threadIdx.x;   // 16384 = 16b x 1024j
  const int b = idx >> 10, j = idx & 1023;
  const float* ig = img_gates + ((size_t)(b * N_ + n)) * G4_;
  float gi = ig[j], gf = ig[1024 + j], gg = ig[2048 + j], go = ig[3072 + j];
  #pragma unroll
  for (int s = 0; s < 16; ++s) {
    const float* p = gp + ((size_t)s * B_ + b) * G4_;
    gi += p[j]; gf += p[1024 + j]; gg += p[2048 + j]; go += p[3072 + j];
  }
  const float c = cA[idx];
  const float cn = sigmoidf_(gf) * c + sigmoidf_(gi) * tanhf(gg);
  const float hn = sigmoidf_(go) * tanhf(cn);
  cA[idx] = cn; hA[idx] = hn;
}

// layer-1 cell + fused pred; one block per b
__global__ __launch_bounds__(256) void cell1_kernel(
    const float* __restrict__ gp, const float* __restrict__ b1,
    const float* __restrict__ Wout, const float* __restrict__ bout,
    float* __restrict__ hB, float* __restrict__ cB, float* __restrict__ pred_out)
{
  const int b = blockIdx.x, tid = threadIdx.x;
  float part = 0.f;
  #pragma unroll
  for (int it = 0; it < 4; ++it) {
    const int j = tid + it * 256;
    float gi = b1[j], gf = b1[1024 + j], gg = b1[2048 + j], go = b1[3072 + j];
    #pragma unroll
    for (int s = 0; s < 16; ++s) {
      const float* p = gp + ((size_t)s * B_ + b) * G4_;
      gi += p[j]; gf += p[1024 + j]; gg += p[2048 + j]; go += p[3072 + j];
    }
    const int idx = b * H_ + j;
    const float c = cB[idx];
    const float cn = sigmoidf_(gf) * c + sigmoidf_(gi) * tanhf(gg);
    const float hn = sigmoidf_(go) * tanhf(cn);
    cB[idx] = cn; hB[idx] = hn;
    part = fmaf(hn, Wout[j], part);
  }
  __shared__ float red[4];
  const float s = block_reduce_sum256(part, red);
  if (tid == 0) pred_out[b] = 1.0f / (1.0f + expf(-(s + bout[0])));
}

extern "C" void kernel_launch(void* const* d_in, const int* in_sizes, int n_in,
                              void* d_out, int out_size, void* d_ws, size_t ws_size,
                              hipStream_t stream) {
  const float* x       = (const float*)d_in[0];
  const float* W_img   = (const float*)d_in[1];
  const float* b_img   = (const float*)d_in[2];
  const float* W_obj   = (const float*)d_in[3];
  const float* b_obj   = (const float*)d_in[4];
  const float* W_obj2  = (const float*)d_in[5];
  const float* b_obj2  = (const float*)d_in[6];
  const float* W_attn_h= (const float*)d_in[7];
  const float* W_attn_j= (const float*)d_in[8];
  const float* W_ih0   = (const float*)d_in[9];    // (4096, 2048)
  const float* W_hh0   = (const float*)d_in[10];   // (4096, 1024)
  const float* b0      = (const float*)d_in[11];
  const float* W_ih1   = (const float*)d_in[12];   // (4096, 1024)
  const float* W_hh1   = (const float*)d_in[13];   // (4096, 1024)
  const float* b1      = (const float*)d_in[14];
  const float* W_out   = (const float*)d_in[15];
  const float* b_out   = (const float*)d_in[16];
  float* out = (float*)d_out;

  // workspace layout (floats); img buffers overlap dead obj_feat region
  float* ws = (float*)d_ws;
  float* mask     = ws;                                   // 19456
  float* obj_feat = mask + 19456;                         // 19456*1024
  float* a_buf    = obj_feat + (size_t)19456 * 1024;      // 19456*1024
  float* ahp      = a_buf + (size_t)19456 * 1024;         // 8*16*1024
  float* wobj     = ahp + 8 * B_ * DO_;                   // 16*1024
  float* hA       = wobj + B_ * DO_;                      // 16*1024
  float* cA       = hA + B_ * H_;
  float* hB       = cA + B_ * H_;
  float* cB       = hB + B_ * H_;
  float* gp       = cB + B_ * H_;                         // 16*16*4096
  float* img_feat  = obj_feat;                            // overlap (obj_feat dead by then)
  float* img_gates = obj_feat + (1u << 20);               // 1024*4096, inside obj_feat region

  // zero LSTM state (ws is poisoned 0xAA before every launch)
  hipMemsetAsync(hA, 0, (size_t)4 * B_ * H_ * sizeof(float), stream);

  // ---- feedforward ----
  mask_kernel<<<19456, 256, 0, stream>>>(x, mask);
  // obj_feat = (x_obj @ W_obj + b_obj) * mask
  gemm_f32<1, false, true ><<<dim3(152, 8), 256, 0, stream>>>(x, W_obj, 1024, b_obj, mask, obj_feat, 4096, 1024);
  // a = obj_feat @ W_obj2 + b_obj2
  gemm_f32<0, false, false><<<dim3(152, 8), 256, 0, stream>>>(obj_feat, W_obj2, 1024, b_obj2, nullptr, a_buf, 1024, 1024);
  // img_feat = x_img @ W_img + b_img   (overwrites dead obj_feat region)
  gemm_f32<2, false, false><<<dim3(8, 8), 256, 0, stream>>>(x, W_img, 1024, b_img, nullptr, img_feat, 4096, 1024);
  // img_gates = img_feat @ W_ih0[:, :1024]^T + b0
  gemm_f32<0, true, false ><<<dim3(8, 32), 256, 0, stream>>>(img_feat, W_ih0, 2048, b0, nullptr, img_gates, 1024, 4096);

  // ---- sequential scan ----
  for (int n = 0; n < N_; ++n) {
    attn_h_kernel<<<dim3(4, 8), 256, 0, stream>>>(hB, W_attn_h, ahp);
    attn_rest_kernel<<<B_, 256, 0, stream>>>(ahp, a_buf, W_attn_j, mask, n,
                                             out + (size_t)n * (B_ * KM1), wobj);
    // layer 0: [wobj | hA] against [W_ih0[:,1024:] | W_hh0]
    gates_kernel<<<dim3(16, 16), 128, 0, stream>>>(wobj, hA, W_ih0, 2048, 1024,
                                                   W_hh0, 1024, 0, gp);
    cell0_kernel<<<64, 256, 0, stream>>>(gp, img_gates, n, hA, cA);
    // layer 1: [hA | hB] against [W_ih1 | W_hh1]
    gates_kernel<<<dim3(16, 16), 128, 0, stream>>>(hA, hB, W_ih1, 1024, 0,
                                                   W_hh1, 1024, 0, gp);
    cell1_kernel<<<B_, 256, 0, stream>>>(gp, b1, W_out, b_out, hB, cB,
                                         out + (size_t)N_ * B_ * KM1 + (size_t)n * B_);
  }
}

// Round 2
// 8587.505 us; speedup vs baseline: 1.2547x; 1.2547x over previous
//
#include <hip/hip_runtime.h>
#include <cmath>

// Problem constants
constexpr int B_  = 16;    // batch
constexpr int N_  = 64;    // frames (scan length)
constexpr int K_  = 20;    // objects incl. image slot
constexpr int KM1 = 19;    // objects
constexpr int D_  = 4096;  // input feature dim
constexpr int DO_ = 1024;
constexpr int H_  = 1024;
constexpr int G4_ = 4096;  // 4*H

static __device__ __forceinline__ float sigmoidf_(float x) {
  return 1.0f / (1.0f + expf(-x));
}

// 256-thread (4-wave) block sum reduction
static __device__ __forceinline__ float block_reduce_sum256(float v, float* red) {
  #pragma unroll
  for (int off = 32; off > 0; off >>= 1) v += __shfl_down(v, off);
  const int wid = threadIdx.x >> 6;
  if ((threadIdx.x & 63) == 0) red[wid] = v;
  __syncthreads();
  const float r = red[0] + red[1] + red[2] + red[3];
  __syncthreads();
  return r;
}

// obj_mask[r] = sum_d x[b, n, 1+kk, d],  r = (b*N + n)*19 + kk
__global__ __launch_bounds__(256) void mask_kernel(const float* __restrict__ x,
                                                   float* __restrict__ mask) {
  const int r = blockIdx.x;
  const int g = r / KM1, kk = r - g * KM1;
  const float4* xp = (const float4*)(x + ((size_t)g * K_ + 1 + kk) * D_);
  float v = 0.f;
  #pragma unroll
  for (int it = 0; it < 4; ++it) {
    const float4 t = xp[threadIdx.x + it * 256];
    v += (t.x + t.y) + (t.z + t.w);
  }
  __shared__ float red[4];
  const float s = block_reduce_sum256(v, red);
  if (threadIdx.x == 0) mask[r] = s;
}

// Generic fp32 GEMM: C[M,N] = (A @ B + bias) [* scale_row]
// AMODE 0: A row r at A + r*Kk; AMODE 1: A row r is x[b,n,1+kk,:]; AMODE 2: row r at A + r*K_*D_
// BTRANS: B element (k,n) at Bm[n*ldb + k]
template<int AMODE, bool BTRANS, bool SCALE>
__global__ __launch_bounds__(256) void gemm_f32(
    const float* __restrict__ A, const float* __restrict__ Bm, const int ldb,
    const float* __restrict__ bias, const float* __restrict__ scale,
    float* __restrict__ C, const int Kk, const int Nn)
{
  constexpr int BM = 128, BN = 128, BK = 16;
  __shared__ float As[BK][BM + 4];
  __shared__ float Bs[BK][BN + 4];
  const int tid = threadIdx.x;
  const int m0 = blockIdx.x * BM, n0 = blockIdx.y * BN;
  const int tm = tid & 15, tn = tid >> 4;

  const float* arow[2];
  #pragma unroll
  for (int it = 0; it < 2; ++it) {
    const int m = (tid + it * 256) >> 2;
    const int row = m0 + m;
    if (AMODE == 0)      arow[it] = A + (size_t)row * Kk;
    else if (AMODE == 1) { const int g = row / KM1, kk2 = row - g * KM1;
                           arow[it] = A + ((size_t)g * K_ + 1 + kk2) * D_; }
    else                 arow[it] = A + (size_t)row * (K_ * D_);
  }
  const int akq = (tid & 3) * 4;

  float acc[8][8] = {};
  for (int k0 = 0; k0 < Kk; k0 += BK) {
    #pragma unroll
    for (int it = 0; it < 2; ++it) {
      const int m = (tid + it * 256) >> 2;
      const float4 v = *(const float4*)(arow[it] + k0 + akq);
      As[akq + 0][m] = v.x; As[akq + 1][m] = v.y;
      As[akq + 2][m] = v.z; As[akq + 3][m] = v.w;
    }
    if (!BTRANS) {
      #pragma unroll
      for (int it = 0; it < 2; ++it) {
        const int idx = tid + it * 256;
        const int k = idx >> 5, n4 = (idx & 31) * 4;
        *(float4*)&Bs[k][n4] = *(const float4*)(Bm + (size_t)(k0 + k) * ldb + n0 + n4);
      }
    } else {
      #pragma unroll
      for (int it = 0; it < 2; ++it) {
        const int idx = tid + it * 256;
        const int kq = (idx & 3) * 4, nr = idx >> 2;
        const float4 v = *(const float4*)(Bm + (size_t)(n0 + nr) * ldb + k0 + kq);
        Bs[kq + 0][nr] = v.x; Bs[kq + 1][nr] = v.y;
        Bs[kq + 2][nr] = v.z; Bs[kq + 3][nr] = v.w;
      }
    }
    __syncthreads();
    #pragma unroll
    for (int k = 0; k < BK; ++k) {
      float av[8], bv[8];
      *(float4*)&av[0] = *(const float4*)&As[k][tm * 8];
      *(float4*)&av[4] = *(const float4*)&As[k][tm * 8 + 4];
      *(float4*)&bv[0] = *(const float4*)&Bs[k][tn * 8];
      *(float4*)&bv[4] = *(const float4*)&Bs[k][tn * 8 + 4];
      #pragma unroll
      for (int r = 0; r < 8; ++r)
        #pragma unroll
        for (int s = 0; s < 8; ++s)
          acc[r][s] = fmaf(av[r], bv[s], acc[r][s]);
    }
    __syncthreads();
  }
  #pragma unroll
  for (int r = 0; r < 8; ++r) {
    const int row = m0 + tm * 8 + r;
    const float sc = SCALE ? scale[row] : 1.0f;
    #pragma unroll
    for (int s4 = 0; s4 < 8; s4 += 4) {
      const int n = n0 + tn * 8 + s4;
      float4 o;
      o.x = (acc[r][s4 + 0] + bias[n + 0]) * sc;
      o.y = (acc[r][s4 + 1] + bias[n + 1]) * sc;
      o.z = (acc[r][s4 + 2] + bias[n + 2]) * sc;
      o.w = (acc[r][s4 + 3] + bias[n + 3]) * sc;
      *(float4*)(C + (size_t)row * Nn + n) = o;
    }
  }
}

// attn hidden partials: ahp[isl][b][j] = sum_{i in slice} hB[b][i] * Wah[i][j]
__global__ __launch_bounds__(256) void attn_h_kernel(
    const float* __restrict__ hB, const float* __restrict__ Wah, float* __restrict__ ahp)
{
  const int j = blockIdx.x * 256 + threadIdx.x;
  const int isl = blockIdx.y;
  float acc[B_] = {};
  for (int i0 = 0; i0 < 128; i0 += 4) {
    const int i = isl * 128 + i0;
    const float w0 = Wah[(size_t)(i + 0) * DO_ + j];
    const float w1 = Wah[(size_t)(i + 1) * DO_ + j];
    const float w2 = Wah[(size_t)(i + 2) * DO_ + j];
    const float w3 = Wah[(size_t)(i + 3) * DO_ + j];
    #pragma unroll
    for (int b = 0; b < B_; ++b) {
      const float4 hv = *(const float4*)(hB + b * H_ + i);  // wave-uniform scalar load
      acc[b] = fmaf(hv.x, w0, fmaf(hv.y, w1, fmaf(hv.z, w2, fmaf(hv.w, w3, acc[b]))));
    }
  }
  #pragma unroll
  for (int b = 0; b < B_; ++b) ahp[((size_t)isl * B_ + b) * DO_ + j] = acc[b];
}

// scores + softmax + w_obj, one block per batch element b.
// Restructured: a-slice staged to LDS once; 19 scores computed in parallel
// across the 4 waves (wave-shuffle reduce; no serial block reductions).
__global__ __launch_bounds__(256) void attn_rest_kernel(
    const float* __restrict__ ahp, const float* __restrict__ a,
    const float* __restrict__ wj, const float* __restrict__ mask,
    const int n, float* __restrict__ alphas_out, float* __restrict__ wobj)
{
  const int b = blockIdx.x, tid = threadIdx.x;
  __shared__ float ahs[DO_];       // 4 KB
  __shared__ float wjs[DO_];       // 4 KB
  __shared__ float as_[KM1][DO_];  // 76 KB
  __shared__ float sc[KM1 + 1];
  const size_t rowbase = (size_t)(b * N_ + n) * KM1;
  // phase A: reduce attn_h partials; stage wj and a-slice
  #pragma unroll
  for (int it = 0; it < 4; ++it) {
    const int j = tid + it * 256;
    float s = 0.f;
    #pragma unroll
    for (int sl = 0; sl < 8; ++sl) s += ahp[((size_t)sl * B_ + b) * DO_ + j];
    ahs[j] = s;
    wjs[j] = wj[j];
  }
  #pragma unroll
  for (int it = 0; it < 19; ++it) {       // 19*1024/4 = 4864 float4 loads
    const int i = tid + it * 256;
    const int k = i >> 8, jj = (i & 255) * 4;
    *(float4*)&as_[k][jj] = *(const float4*)(a + (rowbase + k) * DO_ + jj);
  }
  __syncthreads();
  // phase B: scores, waves in parallel over k
  const int w = tid >> 6, lane = tid & 63;
  for (int k = w; k < KM1; k += 4) {
    float v = 0.f;
    #pragma unroll
    for (int it = 0; it < 16; ++it) {
      const int j = lane + it * 64;
      v = fmaf(tanhf(ahs[j] + as_[k][j]), wjs[j], v);
    }
    #pragma unroll
    for (int off = 32; off > 0; off >>= 1) v += __shfl_down(v, off);
    if (lane == 0) sc[k] = v * mask[rowbase + k];
  }
  __syncthreads();
  // phase C: softmax (redundant per thread, sc broadcast) + w_obj
  float mx = -1e30f;
  #pragma unroll
  for (int k = 0; k < KM1; ++k) mx = fmaxf(mx, sc[k]);
  float al[KM1];
  float ssum = 0.f;
  #pragma unroll
  for (int k = 0; k < KM1; ++k) { al[k] = expf(sc[k] - mx); ssum += al[k]; }
  const float inv = 1.0f / ssum;
  if (tid < KM1) alphas_out[b * KM1 + tid] = al[tid] * inv;
  #pragma unroll
  for (int it = 0; it < 4; ++it) {
    const int j = tid + it * 256;
    float acc = 0.f;
    #pragma unroll
    for (int k = 0; k < KM1; ++k) acc = fmaf(al[k], as_[k][j], acc);
    wobj[b * DO_ + j] = acc * inv;
  }
}

// LSTM gate partials: gp[ks][b][g] = sum_{k in slice} X[b][k] * W[g][co + k]
// grid (16 g-blocks of 256, 16 k-slices of 128), 256 threads (4 waves),
// per-thread tile 8g x 2b via transposed-W LDS.
__global__ __launch_bounds__(256) void gates_kernel(
    const float* __restrict__ x0, const float* __restrict__ x1,
    const float* __restrict__ W0, const int ld0, const int co0,
    const float* __restrict__ W1, const int ld1, const int co1,
    float* __restrict__ gp)
{
  constexpr int GT = 256, BK = 32, KSL = 128;
  __shared__ float Ws[BK][GT + 4];   // transposed: Ws[k][g]
  __shared__ float Xs[BK][20];       // transposed: Xs[k][b]
  const int tid = threadIdx.x;
  const int g0 = blockIdx.x * GT;
  const int ks = blockIdx.y;
  const int half = ks >> 3;
  const int koff = (ks & 7) * KSL;
  const float* X = half ? x1 : x0;
  const float* W = half ? W1 : W0;
  const int ld = half ? ld1 : ld0;
  const int co = half ? co1 : co0;
  const int tb = (tid & 7) * 2;        // b base (2 per thread)
  const int tg = (tid >> 3) * 8;       // g base (8 per thread)
  // hoisted staging base: row g0 + (tid>>3), col chunk (tid&7)*4
  const float* wbase = W + (size_t)(g0 + (tid >> 3)) * ld + co + koff + (tid & 7) * 4;
  const int xb = tid & 15, xkq = (tid >> 4) * 4;   // used by tid<128

  float acc[2][8] = {};                // [bi][gi]
  for (int k0 = 0; k0 < KSL; k0 += BK) {
    #pragma unroll
    for (int it = 0; it < 8; ++it) {   // stage W tile (256 g x 32 k), transposed
      const int gr = (tid >> 3) + it * 32;
      const int kq = (tid & 7) * 4;
      const float4 v = *(const float4*)(wbase + (size_t)it * 32 * ld + k0);
      Ws[kq + 0][gr] = v.x; Ws[kq + 1][gr] = v.y;
      Ws[kq + 2][gr] = v.z; Ws[kq + 3][gr] = v.w;
    }
    if (tid < 128) {                   // stage X tile (16 b x 32 k), transposed
      const float4 v = *(const float4*)(X + (size_t)xb * H_ + koff + k0 + xkq);
      Xs[xkq + 0][xb] = v.x; Xs[xkq + 1][xb] = v.y;
      Xs[xkq + 2][xb] = v.z; Xs[xkq + 3][xb] = v.w;
    }
    __syncthreads();
    #pragma unroll
    for (int k = 0; k < BK; ++k) {
      float wv[8], xv[2];
      *(float4*)&wv[0] = *(const float4*)&Ws[k][tg];
      *(float4*)&wv[4] = *(const float4*)&Ws[k][tg + 4];
      *(float2*)&xv[0] = *(const float2*)&Xs[k][tb];
      #pragma unroll
      for (int bi = 0; bi < 2; ++bi)
        #pragma unroll
        for (int gi = 0; gi < 8; ++gi)
          acc[bi][gi] = fmaf(wv[gi], xv[bi], acc[bi][gi]);
    }
    __syncthreads();
  }
  float* outp = gp + (size_t)ks * B_ * G4_;
  #pragma unroll
  for (int bi = 0; bi < 2; ++bi) {
    float* op = outp + (size_t)(tb + bi) * G4_ + g0 + tg;
    *(float4*)(op)     = *(const float4*)&acc[bi][0];
    *(float4*)(op + 4) = *(const float4*)&acc[bi][4];
  }
}

// layer-0 cell: gates = img_gates[(b,n)] (incl. b0) + sum of 16 partials
__global__ __launch_bounds__(256) void cell0_kernel(
    const float* __restrict__ gp, const float* __restrict__ img_gates, const int n,
    float* __restrict__ hA, float* __restrict__ cA)
{
  const int idx = blockIdx.x * 256 + threadIdx.x;   // 16384 = 16b x 1024j
  const int b = idx >> 10, j = idx & 1023;
  const float* ig = img_gates + ((size_t)(b * N_ + n)) * G4_;
  float gi = ig[j], gf = ig[1024 + j], gg = ig[2048 + j], go = ig[3072 + j];
  #pragma unroll
  for (int s = 0; s < 16; ++s) {
    const float* p = gp + ((size_t)s * B_ + b) * G4_;
    gi += p[j]; gf += p[1024 + j]; gg += p[2048 + j]; go += p[3072 + j];
  }
  const float c = cA[idx];
  const float cn = sigmoidf_(gf) * c + sigmoidf_(gi) * tanhf(gg);
  const float hn = sigmoidf_(go) * tanhf(cn);
  cA[idx] = cn; hA[idx] = hn;
}

// layer-1 cell; 64 blocks (4 per b); pred partial via atomicAdd
__global__ __launch_bounds__(256) void cell1_kernel(
    const float* __restrict__ gp, const float* __restrict__ b1,
    const float* __restrict__ Wout,
    float* __restrict__ hB, float* __restrict__ cB, float* __restrict__ pred_acc)
{
  const int b = blockIdx.x >> 2, jq = blockIdx.x & 3, tid = threadIdx.x;
  const int j = jq * 256 + tid;
  float gi = b1[j], gf = b1[1024 + j], gg = b1[2048 + j], go = b1[3072 + j];
  #pragma unroll
  for (int s = 0; s < 16; ++s) {
    const float* p = gp + ((size_t)s * B_ + b) * G4_;
    gi += p[j]; gf += p[1024 + j]; gg += p[2048 + j]; go += p[3072 + j];
  }
  const int idx = b * H_ + j;
  const float c = cB[idx];
  const float cn = sigmoidf_(gf) * c + sigmoidf_(gi) * tanhf(gg);
  const float hn = sigmoidf_(go) * tanhf(cn);
  cB[idx] = cn; hB[idx] = hn;
  float part = hn * Wout[j];
  __shared__ float red[4];
  const float s = block_reduce_sum256(part, red);
  if (tid == 0) atomicAdd(&pred_acc[b], s);
}

// final: sigmoid over all (n,b) pred accumulators
__global__ __launch_bounds__(256) void pred_kernel(
    const float* __restrict__ pred_acc, const float* __restrict__ bout,
    float* __restrict__ out_pred)
{
  const float bo = bout[0];
  #pragma unroll
  for (int it = 0; it < 4; ++it) {
    const int i = threadIdx.x + it * 256;
    out_pred[i] = 1.0f / (1.0f + expf(-(pred_acc[i] + bo)));
  }
}

extern "C" void kernel_launch(void* const* d_in, const int* in_sizes, int n_in,
                              void* d_out, int out_size, void* d_ws, size_t ws_size,
                              hipStream_t stream) {
  const float* x       = (const float*)d_in[0];
  const float* W_img   = (const float*)d_in[1];
  const float* b_img   = (const float*)d_in[2];
  const float* W_obj   = (const float*)d_in[3];
  const float* b_obj   = (const float*)d_in[4];
  const float* W_obj2  = (const float*)d_in[5];
  const float* b_obj2  = (const float*)d_in[6];
  const float* W_attn_h= (const float*)d_in[7];
  const float* W_attn_j= (const float*)d_in[8];
  const float* W_ih0   = (const float*)d_in[9];    // (4096, 2048)
  const float* W_hh0   = (const float*)d_in[10];   // (4096, 1024)
  const float* b0      = (const float*)d_in[11];
  const float* W_ih1   = (const float*)d_in[12];   // (4096, 1024)
  const float* W_hh1   = (const float*)d_in[13];   // (4096, 1024)
  const float* b1      = (const float*)d_in[14];
  const float* W_out   = (const float*)d_in[15];
  const float* b_out   = (const float*)d_in[16];
  float* out = (float*)d_out;

  // workspace layout (floats); img buffers overlap dead obj_feat region
  float* ws = (float*)d_ws;
  float* mask     = ws;                                   // 19456
  float* obj_feat = mask + 19456;                         // 19456*1024
  float* a_buf    = obj_feat + (size_t)19456 * 1024;      // 19456*1024
  float* ahp      = a_buf + (size_t)19456 * 1024;         // 8*16*1024
  float* wobj     = ahp + 8 * B_ * DO_;                   // 16*1024
  float* hA       = wobj + B_ * DO_;                      // 16*1024
  float* cA       = hA + B_ * H_;
  float* hB       = cA + B_ * H_;
  float* cB       = hB + B_ * H_;
  float* pred_acc = cB + B_ * H_;                         // 1024 (N*B)
  float* gp       = pred_acc + N_ * B_;                   // 16*16*4096
  float* img_feat  = obj_feat;                            // overlap (obj_feat dead by then)
  float* img_gates = obj_feat + (1u << 20);               // 1024*4096, inside obj_feat region

  // zero LSTM state + pred accumulators (ws is re-poisoned before every launch)
  hipMemsetAsync(hA, 0, ((size_t)4 * B_ * H_ + N_ * B_) * sizeof(float), stream);

  // ---- feedforward ----
  mask_kernel<<<19456, 256, 0, stream>>>(x, mask);
  gemm_f32<1, false, true ><<<dim3(152, 8), 256, 0, stream>>>(x, W_obj, 1024, b_obj, mask, obj_feat, 4096, 1024);
  gemm_f32<0, false, false><<<dim3(152, 8), 256, 0, stream>>>(obj_feat, W_obj2, 1024, b_obj2, nullptr, a_buf, 1024, 1024);
  gemm_f32<2, false, false><<<dim3(8, 8), 256, 0, stream>>>(x, W_img, 1024, b_img, nullptr, img_feat, 4096, 1024);
  gemm_f32<0, true, false ><<<dim3(8, 32), 256, 0, stream>>>(img_feat, W_ih0, 2048, b0, nullptr, img_gates, 1024, 4096);

  // ---- sequential scan ----
  for (int n = 0; n < N_; ++n) {
    attn_h_kernel<<<dim3(4, 8), 256, 0, stream>>>(hB, W_attn_h, ahp);
    attn_rest_kernel<<<B_, 256, 0, stream>>>(ahp, a_buf, W_attn_j, mask, n,
                                             out + (size_t)n * (B_ * KM1), wobj);
    gates_kernel<<<dim3(16, 16), 256, 0, stream>>>(wobj, hA, W_ih0, 2048, 1024,
                                                   W_hh0, 1024, 0, gp);
    cell0_kernel<<<64, 256, 0, stream>>>(gp, img_gates, n, hA, cA);
    gates_kernel<<<dim3(16, 16), 256, 0, stream>>>(hA, hB, W_ih1, 1024, 0,
                                                   W_hh1, 1024, 0, gp);
    cell1_kernel<<<64, 256, 0, stream>>>(gp, b1, W_out, hB, cB, pred_acc + n * B_);
  }
  pred_kernel<<<1, 256, 0, stream>>>(pred_acc, b_out, out + (size_t)N_ * B_ * KM1);
}